// Round 1
// baseline (844.308 us; speedup 1.0000x reference)
//
#include <hip/hip_runtime.h>

#define NN 10000
#define NE 320000
#define HD 256
#define NL 3

// ---------------- CSR build ----------------

__global__ void hist_deg(const int* __restrict__ dst, int* __restrict__ deg, int E) {
    int e = blockIdx.x * blockDim.x + threadIdx.x;
    if (e < E) atomicAdd(&deg[dst[e]], 1);
}

// single-block exclusive scan over deg -> row_start[0..n], cursor copy, degf
__global__ __launch_bounds__(1024) void scan_csr(const int* __restrict__ deg,
                                                 int* __restrict__ row_start,
                                                 int* __restrict__ cursor,
                                                 float* __restrict__ degf, int n) {
    __shared__ int buf[1024];
    __shared__ int carry;
    int tid = threadIdx.x;
    if (tid == 0) carry = 0;
    __syncthreads();
    for (int base = 0; base < n; base += 1024) {
        int i = base + tid;
        int v = (i < n) ? deg[i] : 0;
        buf[tid] = v;
        __syncthreads();
        for (int off = 1; off < 1024; off <<= 1) {
            int t = (tid >= off) ? buf[tid - off] : 0;
            __syncthreads();
            buf[tid] += t;
            __syncthreads();
        }
        int excl = buf[tid] - v;
        if (i < n) {
            int rs = carry + excl;
            row_start[i] = rs;
            cursor[i] = rs;
            degf[i] = (float)v;
        }
        __syncthreads();
        if (tid == 0) carry += buf[1023];
        __syncthreads();
    }
    if (tid == 0) row_start[n] = carry;
}

__global__ void scatter_src(const int* __restrict__ src, const int* __restrict__ dst,
                            int* __restrict__ cursor, int* __restrict__ src_sorted, int E) {
    int e = blockIdx.x * blockDim.x + threadIdx.x;
    if (e < E) {
        int pos = atomicAdd(&cursor[dst[e]], 1);
        src_sorted[pos] = src[e];
    }
}

// ---------------- fp32 GEMM: C = act(A@B [+ A2@B2] + rowscale*bias) ----------------
// A: [M,K] row-major, B: [K,N] row-major. BM=64, BN=64, BK=16, 256 threads, 4x4/thread.

#define BM 64
#define BN 64
#define BK 16

__global__ __launch_bounds__(256) void gemm_f32(
    const float* __restrict__ A, const float* __restrict__ B,
    const float* __restrict__ A2, const float* __restrict__ B2,
    const float* __restrict__ bias, const float* __restrict__ rowscale,
    float* __restrict__ C, int M, int N, int K, int do_relu)
{
    __shared__ float As[BK][BM + 4];   // row len 68: 16B-aligned rows, conflict-light
    __shared__ float Bs[BK][BN];
    int tid = threadIdx.x;
    int tx = tid & 15, ty = tid >> 4;
    int row0 = blockIdx.x * BM, col0 = blockIdx.y * BN;
    float acc[4][4] = {};
    int npass = (A2 != nullptr) ? 2 : 1;
    for (int pass = 0; pass < npass; ++pass) {
        const float* Ap = pass ? A2 : A;
        const float* Bp = pass ? B2 : B;
        for (int k0 = 0; k0 < K; k0 += BK) {
            // A tile: 64 rows x 16 cols; one float4 per thread
            {
                int r = tid >> 2;            // 0..63
                int kq = (tid & 3) * 4;      // 0,4,8,12
                int gr = row0 + r;
                float4 v = (gr < M) ? *(const float4*)(Ap + (size_t)gr * K + k0 + kq)
                                    : make_float4(0.f, 0.f, 0.f, 0.f);
                As[kq + 0][r] = v.x; As[kq + 1][r] = v.y;
                As[kq + 2][r] = v.z; As[kq + 3][r] = v.w;
            }
            // B tile: 16 rows x 64 cols; one float4 per thread
            {
                int kr = tid >> 4;           // 0..15
                int c4 = (tid & 15) * 4;     // 0..60
                *(float4*)&Bs[kr][c4] = *(const float4*)(Bp + (size_t)(k0 + kr) * N + col0 + c4);
            }
            __syncthreads();
            #pragma unroll
            for (int kk = 0; kk < BK; ++kk) {
                float4 a = *(float4*)&As[kk][ty * 4];
                float4 b = *(float4*)&Bs[kk][tx * 4];
                float av[4] = {a.x, a.y, a.z, a.w};
                float bv[4] = {b.x, b.y, b.z, b.w};
                #pragma unroll
                for (int i = 0; i < 4; ++i)
                    #pragma unroll
                    for (int j = 0; j < 4; ++j)
                        acc[i][j] += av[i] * bv[j];
            }
            __syncthreads();
        }
    }
    #pragma unroll
    for (int i = 0; i < 4; ++i) {
        int gr = row0 + ty * 4 + i;
        if (gr >= M) break;
        float rs = rowscale ? rowscale[gr] : 1.0f;
        #pragma unroll
        for (int j = 0; j < 4; ++j) {
            int gc = col0 + tx * 4 + j;
            float v = acc[i][j] + (bias ? rs * bias[gc] : 0.0f);
            if (do_relu) v = fmaxf(v, 0.0f);
            C[(size_t)gr * N + gc] = v;
        }
    }
}

// ---------------- edge aggregation: Hagg[n] = sum_{e: dst=n} relu(P[src_e] + Q[n] + b1) ----------------

__global__ __launch_bounds__(256) void edge_agg(
    const float* __restrict__ P, const float* __restrict__ Q,
    const float* __restrict__ b1, const int* __restrict__ row_start,
    const int* __restrict__ src_sorted, float* __restrict__ Hagg)
{
    int node = blockIdx.x;
    int c = threadIdx.x;
    float qb = Q[(size_t)node * HD + c] + b1[c];
    float acc = 0.f;
    int s0 = row_start[node], s1 = row_start[node + 1];
    for (int j = s0; j < s1; ++j) {
        int s = src_sorted[j];
        acc += fmaxf(P[(size_t)s * HD + c] + qb, 0.f);
    }
    Hagg[(size_t)node * HD + c] = acc;
}

// ---------------- residual + LayerNorm ----------------

__global__ __launch_bounds__(256) void resid_ln(
    float* __restrict__ x, const float* __restrict__ upd,
    const float* __restrict__ g, const float* __restrict__ b)
{
    __shared__ float ls[4], lq[4];
    int node = blockIdx.x, c = threadIdx.x;
    size_t idx = (size_t)node * HD + c;
    float v = x[idx] + upd[idx];
    float s = v, q = v * v;
    #pragma unroll
    for (int off = 1; off < 64; off <<= 1) {
        s += __shfl_xor(s, off);
        q += __shfl_xor(q, off);
    }
    int wid = c >> 6, lane = c & 63;
    if (lane == 0) { ls[wid] = s; lq[wid] = q; }
    __syncthreads();
    s = ls[0] + ls[1] + ls[2] + ls[3];
    q = lq[0] + lq[1] + lq[2] + lq[3];
    float mu = s * (1.0f / HD);
    float var = q * (1.0f / HD) - mu * mu;
    float inv = rsqrtf(var + 1e-5f);
    x[idx] = (v - mu) * inv * g[c] + b[c];
}

// ---------------- readout ----------------

__global__ __launch_bounds__(256) void colsum(const float* __restrict__ x,
                                              float* __restrict__ gsum, int n) {
    int c = threadIdx.x;
    int r0 = blockIdx.x * 64;
    int r1 = min(r0 + 64, n);
    float s = 0.f;
    for (int r = r0; r < r1; ++r) s += x[(size_t)r * HD + c];
    atomicAdd(&gsum[c], s);
}

__global__ __launch_bounds__(256) void readout_mlp(
    const float* __restrict__ gsum,
    const float* __restrict__ w1, const float* __restrict__ b1,
    const float* __restrict__ w2, const float* __restrict__ b2,
    float* __restrict__ out, float invn)
{
    __shared__ float gl[HD], h1[HD];
    int c = threadIdx.x;
    gl[c] = gsum[c] * invn;
    __syncthreads();
    float a = b1[c];
    for (int k = 0; k < HD; ++k) a += gl[k] * w1[k * HD + c];
    h1[c] = fmaxf(a, 0.f);
    __syncthreads();
    float o = b2[c];
    for (int k = 0; k < HD; ++k) o += h1[k] * w2[k * HD + c];
    out[c] = o;
}

// ---------------- orchestration ----------------

extern "C" void kernel_launch(void* const* d_in, const int* in_sizes, int n_in,
                              void* d_out, int out_size, void* d_ws, size_t ws_size,
                              hipStream_t stream) {
    const float* nf    = (const float*)d_in[0];
    const int*   ei    = (const int*)d_in[1];
    const float* ne_w1 = (const float*)d_in[2];
    const float* ne_b1 = (const float*)d_in[3];
    const float* ne_w2 = (const float*)d_in[4];
    const float* ne_b2 = (const float*)d_in[5];
    const float* mw1   = (const float*)d_in[6];
    const float* mb1   = (const float*)d_in[7];
    const float* mw2   = (const float*)d_in[8];
    const float* mb2   = (const float*)d_in[9];
    const float* uw1   = (const float*)d_in[10];
    const float* ub1   = (const float*)d_in[11];
    const float* uw2   = (const float*)d_in[12];
    const float* ub2   = (const float*)d_in[13];
    const float* lng   = (const float*)d_in[14];
    const float* lnb   = (const float*)d_in[15];
    const float* rw1   = (const float*)d_in[16];
    const float* rb1   = (const float*)d_in[17];
    const float* rw2   = (const float*)d_in[18];
    const float* rb2   = (const float*)d_in[19];

    const int* e_src = ei;
    const int* e_dst = ei + NE;

    char* w = (char*)d_ws;
    size_t off = 0;
    auto alloc = [&](size_t bytes) -> void* {
        void* p = w + off;
        off = (off + bytes + 255) & ~(size_t)255;
        return p;
    };
    const size_t NF = (size_t)NN * HD * sizeof(float);
    float* x    = (float*)alloc(NF);
    float* P    = (float*)alloc(NF);
    float* Q    = (float*)alloc(NF);
    float* Hagg = (float*)alloc(NF);
    float* agg  = (float*)alloc(NF);
    float* hidU = (float*)alloc(NF);
    float* upd  = (float*)alloc(NF);
    float* gsum = (float*)alloc(HD * sizeof(float));
    float* degf = (float*)alloc(NN * sizeof(float));
    int* deg       = (int*)alloc(NN * sizeof(int));
    int* row_start = (int*)alloc((NN + 1) * sizeof(int));
    int* cursor    = (int*)alloc(NN * sizeof(int));
    int* srcs      = (int*)alloc(NE * sizeof(int));

    hipMemsetAsync(deg, 0, NN * sizeof(int), stream);
    hipMemsetAsync(gsum, 0, HD * sizeof(float), stream);

    // CSR build (dst-sorted)
    hist_deg<<<(NE + 255) / 256, 256, 0, stream>>>(e_dst, deg, NE);
    scan_csr<<<1, 1024, 0, stream>>>(deg, row_start, cursor, degf, NN);
    scatter_src<<<(NE + 255) / 256, 256, 0, stream>>>(e_src, e_dst, cursor, srcs, NE);

    dim3 ggrid((NN + BM - 1) / BM, HD / BN);

    // node encoder: x = relu(nf@ne_w1+b1)@ne_w2+b2
    gemm_f32<<<ggrid, 256, 0, stream>>>(nf, ne_w1, nullptr, nullptr, ne_b1, nullptr,
                                        hidU, NN, HD, HD, 1);
    gemm_f32<<<ggrid, 256, 0, stream>>>(hidU, ne_w2, nullptr, nullptr, ne_b2, nullptr,
                                        x, NN, HD, HD, 0);

    for (int l = 0; l < NL; ++l) {
        const float* w1t = mw1 + (size_t)l * 2 * HD * HD;          // rows 0..255
        const float* w1b = w1t + (size_t)HD * HD;                  // rows 256..511
        const float* b1  = mb1 + (size_t)l * HD;
        const float* w2  = mw2 + (size_t)l * HD * HD;
        const float* b2  = mb2 + (size_t)l * HD;
        const float* u1t = uw1 + (size_t)l * 2 * HD * HD;
        const float* u1b = u1t + (size_t)HD * HD;
        const float* b1u = ub1 + (size_t)l * HD;
        const float* u2  = uw2 + (size_t)l * HD * HD;
        const float* b2u = ub2 + (size_t)l * HD;

        // P = x @ w1_top ; Q = x @ w1_bot   (bias b1 applied in edge_agg)
        gemm_f32<<<ggrid, 256, 0, stream>>>(x, w1t, nullptr, nullptr, nullptr, nullptr,
                                            P, NN, HD, HD, 0);
        gemm_f32<<<ggrid, 256, 0, stream>>>(x, w1b, nullptr, nullptr, nullptr, nullptr,
                                            Q, NN, HD, HD, 0);
        // Hagg[n] = sum_{e->n} relu(P[src]+Q[n]+b1)
        edge_agg<<<NN, 256, 0, stream>>>(P, Q, b1, row_start, srcs, Hagg);
        // aggregated = Hagg @ w2 + deg*b2
        gemm_f32<<<ggrid, 256, 0, stream>>>(Hagg, w2, nullptr, nullptr, b2, degf,
                                            agg, NN, HD, HD, 0);
        // hidU = relu(x@u1_top + agg@u1_bot + b1u)
        gemm_f32<<<ggrid, 256, 0, stream>>>(x, u1t, agg, u1b, b1u, nullptr,
                                            hidU, NN, HD, HD, 1);
        // upd = hidU @ u2 + b2u
        gemm_f32<<<ggrid, 256, 0, stream>>>(hidU, u2, nullptr, nullptr, b2u, nullptr,
                                            upd, NN, HD, HD, 0);
        // x = LN(x + upd) * g + b
        resid_ln<<<NN, 256, 0, stream>>>(x, upd, lng + (size_t)l * HD, lnb + (size_t)l * HD);
    }

    // readout: out = mlp2(mean(x, axis=0))
    colsum<<<(NN + 63) / 64, 256, 0, stream>>>(x, gsum, NN);
    readout_mlp<<<1, 256, 0, stream>>>(gsum, rw1, rb1, rw2, rb2,
                                       (float*)d_out, 1.0f / NN);
}

// Round 2
// 519.902 us; speedup vs baseline: 1.6240x; 1.6240x over previous
//
#include <hip/hip_runtime.h>

#define NN 10000
#define NE 320000
#define HD 256
#define NL 3

typedef unsigned short ushort_t;
typedef __attribute__((ext_vector_type(8))) short bf16x8;
typedef __attribute__((ext_vector_type(4))) float f32x4;

__device__ __forceinline__ unsigned short f2bf(float x) {
    unsigned u = __float_as_uint(x);
    unsigned rounding = 0x7FFFu + ((u >> 16) & 1u);
    return (unsigned short)((u + rounding) >> 16);
}
__device__ __forceinline__ float bf2f(unsigned short u) {
    return __uint_as_float(((unsigned)u) << 16);
}

// ---------------- CSR build ----------------

__global__ void hist_deg(const int* __restrict__ dst, int* __restrict__ deg, int E) {
    int e = blockIdx.x * blockDim.x + threadIdx.x;
    if (e < E) atomicAdd(&deg[dst[e]], 1);
}

__global__ __launch_bounds__(1024) void scan_csr(const int* __restrict__ deg,
                                                 int* __restrict__ row_start,
                                                 int* __restrict__ cursor,
                                                 float* __restrict__ degf, int n) {
    __shared__ int wsum[16];
    __shared__ int carry_s;
    int tid = threadIdx.x, lane = tid & 63, wid = tid >> 6;
    if (tid == 0) carry_s = 0;
    __syncthreads();
    for (int base = 0; base < n; base += 1024) {
        int i = base + tid;
        int v = (i < n) ? deg[i] : 0;
        int s = v;
        #pragma unroll
        for (int off = 1; off < 64; off <<= 1) {
            int t = __shfl_up(s, off);
            if (lane >= off) s += t;
        }
        if (lane == 63) wsum[wid] = s;
        __syncthreads();                                 // B1
        if (wid == 0 && lane < 16) {
            int ws = wsum[lane];
            #pragma unroll
            for (int off = 1; off < 16; off <<= 1) {
                int t = __shfl_up(ws, off);
                if (lane >= off) ws += t;
            }
            wsum[lane] = ws;
        }
        __syncthreads();                                 // B2
        int carry = carry_s;
        int wpre = (wid > 0) ? wsum[wid - 1] : 0;
        int incl = carry + wpre + s;
        int excl = incl - v;
        if (i < n) { row_start[i] = excl; cursor[i] = excl; degf[i] = (float)v; }
        __syncthreads();                                 // B3 (all reads of carry_s/wsum done)
        if (tid == 1023) carry_s = incl;
        __syncthreads();                                 // B4
    }
    if (tid == 0) row_start[n] = carry_s;
}

__global__ void scatter_src(const int* __restrict__ src, const int* __restrict__ dst,
                            int* __restrict__ cursor, int* __restrict__ src_sorted, int E) {
    int e = blockIdx.x * blockDim.x + threadIdx.x;
    if (e < E) {
        int pos = atomicAdd(&cursor[dst[e]], 1);
        src_sorted[pos] = src[e];
    }
}

// ---------------- conversions ----------------

__global__ void cast_bf16(const float* __restrict__ in, ushort_t* __restrict__ out, int n4) {
    int i = blockIdx.x * blockDim.x + threadIdx.x;
    if (i < n4) {
        float4 v = ((const float4*)in)[i];
        ushort4 o = { f2bf(v.x), f2bf(v.y), f2bf(v.z), f2bf(v.w) };
        ((ushort4*)out)[i] = o;
    }
}

struct TDesc { const float* src; ushort_t* dst; };
struct TArgs { TDesc d[17]; };

// transpose-convert: src fp32 [256][256] row-major -> dst bf16 [256][256] = src^T
__global__ __launch_bounds__(256) void conv_t(TArgs args) {
    __shared__ ushort_t tile[64][65];
    const float* src = args.d[blockIdx.y].src;
    ushort_t* dst = args.d[blockIdx.y].dst;
    int t = blockIdx.x;                  // 16 tiles of 64x64
    int r0 = (t >> 2) * 64, c0 = (t & 3) * 64;
    int tid = threadIdx.x;
    int rr = tid >> 4, cc4 = (tid & 15) * 4;
    #pragma unroll
    for (int i = 0; i < 4; ++i) {
        int r = rr + i * 16;
        float4 v = *(const float4*)(src + (size_t)(r0 + r) * HD + c0 + cc4);
        tile[cc4 + 0][r] = f2bf(v.x);
        tile[cc4 + 1][r] = f2bf(v.y);
        tile[cc4 + 2][r] = f2bf(v.z);
        tile[cc4 + 3][r] = f2bf(v.w);
    }
    __syncthreads();
    #pragma unroll
    for (int i = 0; i < 4; ++i) {
        int c = rr + i * 16;
        ushort4 o = { tile[c][cc4], tile[c][cc4 + 1], tile[c][cc4 + 2], tile[c][cc4 + 3] };
        *(ushort4*)(dst + (size_t)(c0 + c) * HD + r0 + cc4) = o;
    }
}

// b2u1[l][c] = sum_k b2[l][k] * u1b[l][k][c]   (fp32, exact fold of deg*b2 through u1b)
__global__ __launch_bounds__(256) void bias_compose(const float* __restrict__ mb2,
                                                    const float* __restrict__ uw1,
                                                    float* __restrict__ out) {
    int l = blockIdx.x, c = threadIdx.x;
    const float* b2l = mb2 + (size_t)l * HD;
    const float* u1b = uw1 + (size_t)l * 2 * HD * HD + (size_t)HD * HD;
    float s = 0.f;
    for (int k = 0; k < HD; ++k) s += b2l[k] * u1b[(size_t)k * HD + c];
    out[(size_t)l * HD + c] = s;
}

// ---------------- bf16 MFMA GEMM ----------------
// C[M][256] = act( A@B [+ A2@B2] + bias + rowscale*bias2 )
// A: bf16 [M][256] row-major. Bt: bf16 [256][256] with Bt[n][k] = B[k][n].
// Block 256 threads = 4 waves (2x2 of 32x32), tile 64x64, K=256 fully unrolled.

__global__ __launch_bounds__(256) void gemm_mfma(
    const ushort_t* __restrict__ A, const ushort_t* __restrict__ Bt,
    const ushort_t* __restrict__ A2, const ushort_t* __restrict__ B2t,
    const float* __restrict__ bias, const float* __restrict__ rowscale,
    const float* __restrict__ bias2,
    float* __restrict__ outF, ushort_t* __restrict__ outB,
    int M, int relu)
{
    int tid = threadIdx.x;
    int wid = tid >> 6, lane = tid & 63;
    int wm = wid >> 1, wn = wid & 1;
    int row0 = blockIdx.x * 64 + wm * 32;
    int col0 = blockIdx.y * 64 + wn * 32;
    int lm = lane & 15;          // m (A) / n (B) index within fragment
    int lk = (lane >> 4) * 8;    // k offset within fragment
    int r0c = min(row0 + lm, M - 1);
    int r1c = min(row0 + 16 + lm, M - 1);

    f32x4 acc[2][2] = {};
    auto run_pass = [&](const ushort_t* Ap, const ushort_t* Btp) {
        const ushort_t* a0p = Ap + (size_t)r0c * HD + lk;
        const ushort_t* a1p = Ap + (size_t)r1c * HD + lk;
        const ushort_t* b0p = Btp + (size_t)(col0 + lm) * HD + lk;
        const ushort_t* b1p = Btp + (size_t)(col0 + 16 + lm) * HD + lk;
        #pragma unroll
        for (int k0 = 0; k0 < HD; k0 += 32) {
            bf16x8 a0 = *(const bf16x8*)(a0p + k0);
            bf16x8 a1 = *(const bf16x8*)(a1p + k0);
            bf16x8 b0 = *(const bf16x8*)(b0p + k0);
            bf16x8 b1 = *(const bf16x8*)(b1p + k0);
            acc[0][0] = __builtin_amdgcn_mfma_f32_16x16x32_bf16(a0, b0, acc[0][0], 0, 0, 0);
            acc[0][1] = __builtin_amdgcn_mfma_f32_16x16x32_bf16(a0, b1, acc[0][1], 0, 0, 0);
            acc[1][0] = __builtin_amdgcn_mfma_f32_16x16x32_bf16(a1, b0, acc[1][0], 0, 0, 0);
            acc[1][1] = __builtin_amdgcn_mfma_f32_16x16x32_bf16(a1, b1, acc[1][1], 0, 0, 0);
        }
    };
    run_pass(A, Bt);
    if (A2) run_pass(A2, B2t);

    int orow = (lane >> 4) * 4;
    #pragma unroll
    for (int mi = 0; mi < 2; ++mi) {
        #pragma unroll
        for (int r = 0; r < 4; ++r) {
            int row = row0 + mi * 16 + orow + r;
            if (row >= M) continue;
            float rs = rowscale ? rowscale[row] : 0.f;
            #pragma unroll
            for (int ni = 0; ni < 2; ++ni) {
                int col = col0 + ni * 16 + lm;
                float v = acc[mi][ni][r];
                if (bias) v += bias[col];
                if (rowscale) v += rs * bias2[col];
                if (relu) v = fmaxf(v, 0.f);
                if (outF) outF[(size_t)row * HD + col] = v;
                if (outB) outB[(size_t)row * HD + col] = f2bf(v);
            }
        }
    }
}

// ---------------- edge aggregation ----------------
// Hagg[n] = sum_{e: dst=n} relu(P[src_e] + Qb[n])   (Qb already has +b1 from GEMM epilogue)
// 1 wave per node, float4 channels per lane, P gathered as bf16 (512B rows).

__global__ __launch_bounds__(256) void edge_agg(
    const ushort_t* __restrict__ Pb, const float* __restrict__ Qb,
    const int* __restrict__ row_start, const int* __restrict__ srcs,
    ushort_t* __restrict__ Haggb)
{
    int node = blockIdx.x * 4 + (threadIdx.x >> 6);
    int lane = threadIdx.x & 63;
    int c4 = lane * 4;
    float4 qb = *(const float4*)(Qb + (size_t)node * HD + c4);
    float4 acc = {0.f, 0.f, 0.f, 0.f};
    int j = row_start[node], e = row_start[node + 1];
    for (; j + 2 <= e; j += 2) {
        int sa = srcs[j], sb = srcs[j + 1];
        ushort4 pa = *(const ushort4*)(Pb + (size_t)sa * HD + c4);
        ushort4 pb = *(const ushort4*)(Pb + (size_t)sb * HD + c4);
        acc.x += fmaxf(bf2f(pa.x) + qb.x, 0.f) + fmaxf(bf2f(pb.x) + qb.x, 0.f);
        acc.y += fmaxf(bf2f(pa.y) + qb.y, 0.f) + fmaxf(bf2f(pb.y) + qb.y, 0.f);
        acc.z += fmaxf(bf2f(pa.z) + qb.z, 0.f) + fmaxf(bf2f(pb.z) + qb.z, 0.f);
        acc.w += fmaxf(bf2f(pa.w) + qb.w, 0.f) + fmaxf(bf2f(pb.w) + qb.w, 0.f);
    }
    if (j < e) {
        int sa = srcs[j];
        ushort4 pa = *(const ushort4*)(Pb + (size_t)sa * HD + c4);
        acc.x += fmaxf(bf2f(pa.x) + qb.x, 0.f);
        acc.y += fmaxf(bf2f(pa.y) + qb.y, 0.f);
        acc.z += fmaxf(bf2f(pa.z) + qb.z, 0.f);
        acc.w += fmaxf(bf2f(pa.w) + qb.w, 0.f);
    }
    ushort4 o = { f2bf(acc.x), f2bf(acc.y), f2bf(acc.z), f2bf(acc.w) };
    *(ushort4*)(Haggb + (size_t)node * HD + c4) = o;
}

// ---------------- residual + LayerNorm (writes fp32 x and bf16 shadow) ----------------

__global__ __launch_bounds__(256) void resid_ln(
    float* __restrict__ x, const float* __restrict__ upd,
    const float* __restrict__ g, const float* __restrict__ b,
    ushort_t* __restrict__ xb)
{
    __shared__ float ls[4], lq[4];
    int node = blockIdx.x, c = threadIdx.x;
    size_t idx = (size_t)node * HD + c;
    float v = x[idx] + upd[idx];
    float s = v, q = v * v;
    #pragma unroll
    for (int off = 1; off < 64; off <<= 1) {
        s += __shfl_xor(s, off);
        q += __shfl_xor(q, off);
    }
    int wid = c >> 6, lane = c & 63;
    if (lane == 0) { ls[wid] = s; lq[wid] = q; }
    __syncthreads();
    s = ls[0] + ls[1] + ls[2] + ls[3];
    q = lq[0] + lq[1] + lq[2] + lq[3];
    float mu = s * (1.0f / HD);
    float var = q * (1.0f / HD) - mu * mu;
    float inv = rsqrtf(var + 1e-5f);
    float o = (v - mu) * inv * g[c] + b[c];
    x[idx] = o;
    xb[idx] = f2bf(o);
}

// ---------------- readout ----------------

__global__ __launch_bounds__(256) void colsum(const float* __restrict__ x,
                                              float* __restrict__ gsum, int n) {
    int c = threadIdx.x;
    int r0 = blockIdx.x * 64;
    int r1 = min(r0 + 64, n);
    float s = 0.f;
    for (int r = r0; r < r1; ++r) s += x[(size_t)r * HD + c];
    atomicAdd(&gsum[c], s);
}

__global__ __launch_bounds__(256) void readout_mlp(
    const float* __restrict__ gsum,
    const float* __restrict__ w1, const float* __restrict__ b1,
    const float* __restrict__ w2, const float* __restrict__ b2,
    float* __restrict__ out, float invn)
{
    __shared__ float gl[HD], h1[HD];
    int c = threadIdx.x;
    gl[c] = gsum[c] * invn;
    __syncthreads();
    float a = b1[c];
    for (int k = 0; k < HD; ++k) a += gl[k] * w1[k * HD + c];
    h1[c] = fmaxf(a, 0.f);
    __syncthreads();
    float o = b2[c];
    for (int k = 0; k < HD; ++k) o += h1[k] * w2[k * HD + c];
    out[c] = o;
}

// ---------------- orchestration ----------------

extern "C" void kernel_launch(void* const* d_in, const int* in_sizes, int n_in,
                              void* d_out, int out_size, void* d_ws, size_t ws_size,
                              hipStream_t stream) {
    const float* nf    = (const float*)d_in[0];
    const int*   ei    = (const int*)d_in[1];
    const float* ne_w1 = (const float*)d_in[2];
    const float* ne_b1 = (const float*)d_in[3];
    const float* ne_w2 = (const float*)d_in[4];
    const float* ne_b2 = (const float*)d_in[5];
    const float* mw1   = (const float*)d_in[6];
    const float* mb1   = (const float*)d_in[7];
    const float* mw2   = (const float*)d_in[8];
    const float* mb2   = (const float*)d_in[9];
    const float* uw1   = (const float*)d_in[10];
    const float* ub1   = (const float*)d_in[11];
    const float* uw2   = (const float*)d_in[12];
    const float* ub2   = (const float*)d_in[13];
    const float* lng   = (const float*)d_in[14];
    const float* lnb   = (const float*)d_in[15];
    const float* rw1   = (const float*)d_in[16];
    const float* rb1   = (const float*)d_in[17];
    const float* rw2   = (const float*)d_in[18];
    const float* rb2   = (const float*)d_in[19];

    const int* e_src = ei;
    const int* e_dst = ei + NE;

    char* w = (char*)d_ws;
    size_t off = 0;
    auto alloc = [&](size_t bytes) -> void* {
        void* p = w + off;
        off = (off + bytes + 255) & ~(size_t)255;
        return p;
    };
    const size_t NF32 = (size_t)NN * HD * sizeof(float);
    const size_t NF16 = (size_t)NN * HD * sizeof(ushort_t);
    const size_t WM16 = (size_t)HD * HD * sizeof(ushort_t);

    float* x    = (float*)alloc(NF32);
    float* Qf   = (float*)alloc(NF32);
    float* updf = (float*)alloc(NF32);
    float* gsum = (float*)alloc(HD * sizeof(float));
    float* degf = (float*)alloc(NN * sizeof(float));
    float* b2u1 = (float*)alloc(NL * HD * sizeof(float));

    ushort_t* nfb   = (ushort_t*)alloc(NF16);
    ushort_t* xb    = (ushort_t*)alloc(NF16);
    ushort_t* hidb  = (ushort_t*)alloc(NF16);
    ushort_t* Pb    = (ushort_t*)alloc(NF16);
    ushort_t* Haggb = (ushort_t*)alloc(NF16);
    ushort_t* neT1  = (ushort_t*)alloc(WM16);
    ushort_t* neT2  = (ushort_t*)alloc(WM16);
    ushort_t* w1tT  = (ushort_t*)alloc(NL * WM16);
    ushort_t* w1bT  = (ushort_t*)alloc(NL * WM16);
    ushort_t* u1tT  = (ushort_t*)alloc(NL * WM16);
    ushort_t* u1bT  = (ushort_t*)alloc(NL * WM16);
    ushort_t* u2T   = (ushort_t*)alloc(NL * WM16);
    ushort_t* w2uT  = (ushort_t*)alloc(NL * WM16);
    ushort_t* w2rmb = (ushort_t*)alloc(NL * WM16);

    int* deg       = (int*)alloc(NN * sizeof(int));
    int* row_start = (int*)alloc((NN + 1) * sizeof(int));
    int* cursor    = (int*)alloc(NN * sizeof(int));
    int* srcs      = (int*)alloc(NE * sizeof(int));

    hipMemsetAsync(deg, 0, NN * sizeof(int), stream);
    hipMemsetAsync(gsum, 0, HD * sizeof(float), stream);

    // CSR build (dst-sorted)
    hist_deg<<<(NE + 255) / 256, 256, 0, stream>>>(e_dst, deg, NE);
    scan_csr<<<1, 1024, 0, stream>>>(deg, row_start, cursor, degf, NN);
    scatter_src<<<(NE + 255) / 256, 256, 0, stream>>>(e_src, e_dst, cursor, srcs, NE);

    // weight conversion
    cast_bf16<<<(NN * HD / 4 + 255) / 256, 256, 0, stream>>>(nf, nfb, NN * HD / 4);
    cast_bf16<<<(NL * HD * HD / 4 + 255) / 256, 256, 0, stream>>>(mw2, w2rmb, NL * HD * HD / 4);

    TArgs ta;
    ta.d[0] = { ne_w1, neT1 };
    ta.d[1] = { ne_w2, neT2 };
    for (int l = 0; l < NL; ++l) {
        const float* w1l = mw1 + (size_t)l * 2 * HD * HD;
        const float* u1l = uw1 + (size_t)l * 2 * HD * HD;
        ta.d[2 + l]  = { w1l,                      w1tT + (size_t)l * HD * HD };
        ta.d[5 + l]  = { w1l + (size_t)HD * HD,    w1bT + (size_t)l * HD * HD };
        ta.d[8 + l]  = { u1l,                      u1tT + (size_t)l * HD * HD };
        ta.d[11 + l] = { u1l + (size_t)HD * HD,    u1bT + (size_t)l * HD * HD };
        ta.d[14 + l] = { uw2 + (size_t)l * HD * HD, u2T + (size_t)l * HD * HD };
    }
    conv_t<<<dim3(16, 17), 256, 0, stream>>>(ta);

    bias_compose<<<NL, 256, 0, stream>>>(mb2, uw1, b2u1);

    // w2uT[l] = (w2[l] @ u1b[l])^T  computed as u1bT @ w2T  (see derivation in journal)
    dim3 sgrid(4, 4);
    for (int l = 0; l < NL; ++l)
        gemm_mfma<<<sgrid, 256, 0, stream>>>(u1bT + (size_t)l * HD * HD,
                                             w2rmb + (size_t)l * HD * HD,
                                             nullptr, nullptr, nullptr, nullptr, nullptr,
                                             nullptr, w2uT + (size_t)l * HD * HD, HD, 0);

    dim3 ggrid((NN + 63) / 64, HD / 64);

    // node encoder
    gemm_mfma<<<ggrid, 256, 0, stream>>>(nfb, neT1, nullptr, nullptr, ne_b1, nullptr, nullptr,
                                         nullptr, hidb, NN, 1);
    gemm_mfma<<<ggrid, 256, 0, stream>>>(hidb, neT2, nullptr, nullptr, ne_b2, nullptr, nullptr,
                                         x, xb, NN, 0);

    for (int l = 0; l < NL; ++l) {
        const ushort_t* w1tl = w1tT + (size_t)l * HD * HD;
        const ushort_t* w1bl = w1bT + (size_t)l * HD * HD;
        const ushort_t* u1tl = u1tT + (size_t)l * HD * HD;
        const ushort_t* u2l  = u2T + (size_t)l * HD * HD;
        const ushort_t* w2ul = w2uT + (size_t)l * HD * HD;

        // P = x @ w1_top (bf16 out);  Q = x @ w1_bot + b1 (fp32 out)
        gemm_mfma<<<ggrid, 256, 0, stream>>>(xb, w1tl, nullptr, nullptr, nullptr, nullptr, nullptr,
                                             nullptr, Pb, NN, 0);
        gemm_mfma<<<ggrid, 256, 0, stream>>>(xb, w1bl, nullptr, nullptr, mb1 + (size_t)l * HD,
                                             nullptr, nullptr, Qf, nullptr, NN, 0);
        // Hagg[n] = sum_{e->n} relu(P[src] + Q[n])
        edge_agg<<<NN / 4, 256, 0, stream>>>(Pb, Qf, row_start, srcs, Haggb);
        // hidU = relu(x@u1t + Hagg@(w2@u1b) + b1u + deg*(b2@u1b))
        gemm_mfma<<<ggrid, 256, 0, stream>>>(xb, u1tl, Haggb, w2ul, ub1 + (size_t)l * HD,
                                             degf, b2u1 + (size_t)l * HD, nullptr, hidb, NN, 1);
        // upd = hidU @ u2 + b2u
        gemm_mfma<<<ggrid, 256, 0, stream>>>(hidb, u2l, nullptr, nullptr, ub2 + (size_t)l * HD,
                                             nullptr, nullptr, updf, nullptr, NN, 0);
        // x = LN(x + upd)
        resid_ln<<<NN, 256, 0, stream>>>(x, updf, lng + (size_t)l * HD, lnb + (size_t)l * HD, xb);
    }

    // readout
    colsum<<<(NN + 63) / 64, 256, 0, stream>>>(x, gsum, NN);
    readout_mlp<<<1, 256, 0, stream>>>(gsum, rw1, rb1, rw2, rb2, (float*)d_out, 1.0f / NN);
}

// Round 3
// 388.516 us; speedup vs baseline: 2.1732x; 1.3382x over previous
//
#include <hip/hip_runtime.h>

#define NN 10000
#define NE 320000
#define HD 256
#define NL 3

typedef unsigned short ushort_t;
typedef __attribute__((ext_vector_type(8))) short bf16x8;
typedef __attribute__((ext_vector_type(4))) float f32x4;

__device__ __forceinline__ unsigned short f2bf(float x) {
    unsigned u = __float_as_uint(x);
    unsigned rounding = 0x7FFFu + ((u >> 16) & 1u);
    return (unsigned short)((u + rounding) >> 16);
}
__device__ __forceinline__ float bf2f(unsigned short u) {
    return __uint_as_float(((unsigned)u) << 16);
}

// ---------------- CSR build ----------------

__global__ void hist_deg(const int* __restrict__ dst, int* __restrict__ deg, int E) {
    int e = blockIdx.x * blockDim.x + threadIdx.x;
    if (e < E) atomicAdd(&deg[dst[e]], 1);
}

__global__ __launch_bounds__(1024) void scan_csr(const int* __restrict__ deg,
                                                 int* __restrict__ row_start,
                                                 int* __restrict__ cursor,
                                                 float* __restrict__ degf, int n) {
    __shared__ int wsum[16];
    __shared__ int carry_s;
    int tid = threadIdx.x, lane = tid & 63, wid = tid >> 6;
    if (tid == 0) carry_s = 0;
    __syncthreads();
    for (int base = 0; base < n; base += 1024) {
        int i = base + tid;
        int v = (i < n) ? deg[i] : 0;
        int s = v;
        #pragma unroll
        for (int off = 1; off < 64; off <<= 1) {
            int t = __shfl_up(s, off);
            if (lane >= off) s += t;
        }
        if (lane == 63) wsum[wid] = s;
        __syncthreads();
        if (wid == 0 && lane < 16) {
            int ws = wsum[lane];
            #pragma unroll
            for (int off = 1; off < 16; off <<= 1) {
                int t = __shfl_up(ws, off);
                if (lane >= off) ws += t;
            }
            wsum[lane] = ws;
        }
        __syncthreads();
        int carry = carry_s;
        int wpre = (wid > 0) ? wsum[wid - 1] : 0;
        int incl = carry + wpre + s;
        int excl = incl - v;
        if (i < n) { row_start[i] = excl; cursor[i] = excl; degf[i] = (float)v; }
        __syncthreads();
        if (tid == 1023) carry_s = incl;
        __syncthreads();
    }
    if (tid == 0) row_start[n] = carry_s;
}

__global__ void scatter_src(const int* __restrict__ src, const int* __restrict__ dst,
                            int* __restrict__ cursor, int* __restrict__ src_sorted, int E) {
    int e = blockIdx.x * blockDim.x + threadIdx.x;
    if (e < E) {
        int pos = atomicAdd(&cursor[dst[e]], 1);
        src_sorted[pos] = src[e];
    }
}

// ---------------- conversions ----------------

__global__ void cast_bf16(const float* __restrict__ in, ushort_t* __restrict__ out, int n4) {
    int i = blockIdx.x * blockDim.x + threadIdx.x;
    if (i < n4) {
        float4 v = ((const float4*)in)[i];
        ushort4 o = { f2bf(v.x), f2bf(v.y), f2bf(v.z), f2bf(v.w) };
        ((ushort4*)out)[i] = o;
    }
}

struct TDesc { const float* src; ushort_t* dst; };
struct TArgs { TDesc d[17]; };

// transpose-convert: src fp32 [256][256] row-major -> dst bf16 [256][256] = src^T
__global__ __launch_bounds__(256) void conv_t(TArgs args) {
    __shared__ ushort_t tile[64][65];
    const float* src = args.d[blockIdx.y].src;
    ushort_t* dst = args.d[blockIdx.y].dst;
    int t = blockIdx.x;
    int r0 = (t >> 2) * 64, c0 = (t & 3) * 64;
    int tid = threadIdx.x;
    int rr = tid >> 4, cc4 = (tid & 15) * 4;
    #pragma unroll
    for (int i = 0; i < 4; ++i) {
        int r = rr + i * 16;
        float4 v = *(const float4*)(src + (size_t)(r0 + r) * HD + c0 + cc4);
        tile[cc4 + 0][r] = f2bf(v.x);
        tile[cc4 + 1][r] = f2bf(v.y);
        tile[cc4 + 2][r] = f2bf(v.z);
        tile[cc4 + 3][r] = f2bf(v.w);
    }
    __syncthreads();
    #pragma unroll
    for (int i = 0; i < 4; ++i) {
        int c = rr + i * 16;
        ushort4 o = { tile[c][cc4], tile[c][cc4 + 1], tile[c][cc4 + 2], tile[c][cc4 + 3] };
        *(ushort4*)(dst + (size_t)(c0 + c) * HD + r0 + cc4) = o;
    }
}

__global__ __launch_bounds__(256) void bias_compose(const float* __restrict__ mb2,
                                                    const float* __restrict__ uw1,
                                                    float* __restrict__ out) {
    int l = blockIdx.x, c = threadIdx.x;
    const float* b2l = mb2 + (size_t)l * HD;
    const float* u1b = uw1 + (size_t)l * 2 * HD * HD + (size_t)HD * HD;
    float s = 0.f;
    for (int k = 0; k < HD; ++k) s += b2l[k] * u1b[(size_t)k * HD + c];
    out[(size_t)l * HD + c] = s;
}

// ---------------- w2u precompute: w2uT[l] = (w2[l]@u1b[l])^T = u1bT[l] (x) w2rm[l] ----------------
// C[m][n] = sum_k A[m][k]*Bt[n][k]; batched over blockIdx.z. M=N=K=256.

__global__ __launch_bounds__(256) void gemm_w2u(
    const ushort_t* __restrict__ Abase, const ushort_t* __restrict__ Btbase,
    ushort_t* __restrict__ outBase)
{
    const ushort_t* A  = Abase  + (size_t)blockIdx.z * HD * HD;
    const ushort_t* Bt = Btbase + (size_t)blockIdx.z * HD * HD;
    ushort_t* outB     = outBase + (size_t)blockIdx.z * HD * HD;
    int tid = threadIdx.x;
    int wid = tid >> 6, lane = tid & 63;
    int wm = wid >> 1, wn = wid & 1;
    int row0 = blockIdx.x * 64 + wm * 32;
    int col0 = blockIdx.y * 64 + wn * 32;
    int lm = lane & 15, lk = (lane >> 4) * 8;
    f32x4 acc[2][2] = {};
    const ushort_t* a0p = A + (size_t)(row0 + lm) * HD + lk;
    const ushort_t* a1p = A + (size_t)(row0 + 16 + lm) * HD + lk;
    const ushort_t* b0p = Bt + (size_t)(col0 + lm) * HD + lk;
    const ushort_t* b1p = Bt + (size_t)(col0 + 16 + lm) * HD + lk;
    #pragma unroll
    for (int k0 = 0; k0 < HD; k0 += 32) {
        bf16x8 a0 = *(const bf16x8*)(a0p + k0);
        bf16x8 a1 = *(const bf16x8*)(a1p + k0);
        bf16x8 b0 = *(const bf16x8*)(b0p + k0);
        bf16x8 b1 = *(const bf16x8*)(b1p + k0);
        acc[0][0] = __builtin_amdgcn_mfma_f32_16x16x32_bf16(a0, b0, acc[0][0], 0, 0, 0);
        acc[0][1] = __builtin_amdgcn_mfma_f32_16x16x32_bf16(a0, b1, acc[0][1], 0, 0, 0);
        acc[1][0] = __builtin_amdgcn_mfma_f32_16x16x32_bf16(a1, b0, acc[1][0], 0, 0, 0);
        acc[1][1] = __builtin_amdgcn_mfma_f32_16x16x32_bf16(a1, b1, acc[1][1], 0, 0, 0);
    }
    int orow = (lane >> 4) * 4;
    #pragma unroll
    for (int mi = 0; mi < 2; ++mi)
        #pragma unroll
        for (int r = 0; r < 4; ++r) {
            int row = row0 + mi * 16 + orow + r;
            #pragma unroll
            for (int ni = 0; ni < 2; ++ni) {
                int col = col0 + ni * 16 + lm;
                outB[(size_t)row * HD + col] = f2bf(acc[mi][ni][r]);
            }
        }
}

// ---------------- fused P/Q GEMM ----------------
// P = x@w1t (bf16 out), Q = x@w1b + b1 (f32 out). Shared A-fragments.

__global__ __launch_bounds__(256) void gemm_pq(
    const ushort_t* __restrict__ A, const ushort_t* __restrict__ Bpt,
    const ushort_t* __restrict__ Bqt, const float* __restrict__ b1,
    ushort_t* __restrict__ P, float* __restrict__ Q, int M)
{
    int tid = threadIdx.x;
    int wid = tid >> 6, lane = tid & 63;
    int wm = wid >> 1, wn = wid & 1;
    int row0 = blockIdx.x * 64 + wm * 32;
    int col0 = blockIdx.y * 64 + wn * 32;
    int lm = lane & 15, q = lane >> 4, lk = q * 8;
    int ra = min(row0 + lm, M - 1), rb = min(row0 + 16 + lm, M - 1);
    f32x4 aP[2][2] = {}, aQ[2][2] = {};
    const ushort_t* a0p = A + (size_t)ra * HD + lk;
    const ushort_t* a1p = A + (size_t)rb * HD + lk;
    const ushort_t* p0p = Bpt + (size_t)(col0 + lm) * HD + lk;
    const ushort_t* p1p = Bpt + (size_t)(col0 + 16 + lm) * HD + lk;
    const ushort_t* q0p = Bqt + (size_t)(col0 + lm) * HD + lk;
    const ushort_t* q1p = Bqt + (size_t)(col0 + 16 + lm) * HD + lk;
    #pragma unroll
    for (int k0 = 0; k0 < HD; k0 += 32) {
        bf16x8 a0 = *(const bf16x8*)(a0p + k0);
        bf16x8 a1 = *(const bf16x8*)(a1p + k0);
        bf16x8 p0 = *(const bf16x8*)(p0p + k0);
        bf16x8 p1 = *(const bf16x8*)(p1p + k0);
        bf16x8 q0 = *(const bf16x8*)(q0p + k0);
        bf16x8 q1 = *(const bf16x8*)(q1p + k0);
        aP[0][0] = __builtin_amdgcn_mfma_f32_16x16x32_bf16(a0, p0, aP[0][0], 0, 0, 0);
        aP[0][1] = __builtin_amdgcn_mfma_f32_16x16x32_bf16(a0, p1, aP[0][1], 0, 0, 0);
        aP[1][0] = __builtin_amdgcn_mfma_f32_16x16x32_bf16(a1, p0, aP[1][0], 0, 0, 0);
        aP[1][1] = __builtin_amdgcn_mfma_f32_16x16x32_bf16(a1, p1, aP[1][1], 0, 0, 0);
        aQ[0][0] = __builtin_amdgcn_mfma_f32_16x16x32_bf16(a0, q0, aQ[0][0], 0, 0, 0);
        aQ[0][1] = __builtin_amdgcn_mfma_f32_16x16x32_bf16(a0, q1, aQ[0][1], 0, 0, 0);
        aQ[1][0] = __builtin_amdgcn_mfma_f32_16x16x32_bf16(a1, q0, aQ[1][0], 0, 0, 0);
        aQ[1][1] = __builtin_amdgcn_mfma_f32_16x16x32_bf16(a1, q1, aQ[1][1], 0, 0, 0);
    }
    int orow = q * 4;
    #pragma unroll
    for (int mi = 0; mi < 2; ++mi)
        #pragma unroll
        for (int r = 0; r < 4; ++r) {
            int row = row0 + mi * 16 + orow + r;
            if (row >= M) continue;
            #pragma unroll
            for (int ni = 0; ni < 2; ++ni) {
                int col = col0 + ni * 16 + lm;
                P[(size_t)row * HD + col] = f2bf(aP[mi][ni][r]);
                Q[(size_t)row * HD + col] = aQ[mi][ni][r] + b1[col];
            }
        }
}

// ---------------- LDS swizzle helper (G4: row-major [32][256] bf16 is 32-way conflict) ----------------
__device__ __forceinline__ int swz(int row, int byte_in_row) {
    return row * 512 + (byte_in_row ^ ((row & 7) << 4));
}

// ---------------- fused encoder: x = relu(nf@W1+b1)@W2 + b2 ----------------
// Block: 32 rows x 256 cols; 4 waves, wave w owns cols [64w,64w+64).

__global__ __launch_bounds__(256) void enc_fused(
    const ushort_t* __restrict__ A, const ushort_t* __restrict__ B1t,
    const ushort_t* __restrict__ B2t,
    const float* __restrict__ b1, const float* __restrict__ b2,
    float* __restrict__ xF, ushort_t* __restrict__ xB, int M)
{
    __shared__ char hid[32 * 512];
    int tid = threadIdx.x;
    int w = tid >> 6, lane = tid & 63;
    int lm = lane & 15, q = lane >> 4, lk = q * 8;
    int row0 = blockIdx.x * 32;
    int col0 = w * 64;
    int ra = min(row0 + lm, M - 1), rb = min(row0 + 16 + lm, M - 1);

    f32x4 acc[2][4] = {};
    #pragma unroll
    for (int k0 = 0; k0 < HD; k0 += 32) {
        bf16x8 a0 = *(const bf16x8*)(A + (size_t)ra * HD + k0 + lk);
        bf16x8 a1 = *(const bf16x8*)(A + (size_t)rb * HD + k0 + lk);
        #pragma unroll
        for (int ni = 0; ni < 4; ++ni) {
            bf16x8 b = *(const bf16x8*)(B1t + (size_t)(col0 + 16 * ni + lm) * HD + k0 + lk);
            acc[0][ni] = __builtin_amdgcn_mfma_f32_16x16x32_bf16(a0, b, acc[0][ni], 0, 0, 0);
            acc[1][ni] = __builtin_amdgcn_mfma_f32_16x16x32_bf16(a1, b, acc[1][ni], 0, 0, 0);
        }
    }
    #pragma unroll
    for (int mi = 0; mi < 2; ++mi)
        #pragma unroll
        for (int ni = 0; ni < 4; ++ni) {
            int col = col0 + 16 * ni + lm;
            float bias = b1[col];
            #pragma unroll
            for (int r = 0; r < 4; ++r) {
                int row = 16 * mi + 4 * q + r;
                float v = fmaxf(acc[mi][ni][r] + bias, 0.f);
                *(ushort_t*)(hid + swz(row, col * 2)) = f2bf(v);
            }
        }
    __syncthreads();
    f32x4 acc2[2][4] = {};
    #pragma unroll
    for (int k0 = 0; k0 < HD; k0 += 32) {
        int bk = (k0 + lk) * 2;
        bf16x8 a0 = *(const bf16x8*)(hid + swz(lm, bk));
        bf16x8 a1 = *(const bf16x8*)(hid + swz(16 + lm, bk));
        #pragma unroll
        for (int ni = 0; ni < 4; ++ni) {
            bf16x8 b = *(const bf16x8*)(B2t + (size_t)(col0 + 16 * ni + lm) * HD + k0 + lk);
            acc2[0][ni] = __builtin_amdgcn_mfma_f32_16x16x32_bf16(a0, b, acc2[0][ni], 0, 0, 0);
            acc2[1][ni] = __builtin_amdgcn_mfma_f32_16x16x32_bf16(a1, b, acc2[1][ni], 0, 0, 0);
        }
    }
    #pragma unroll
    for (int mi = 0; mi < 2; ++mi)
        #pragma unroll
        for (int ni = 0; ni < 4; ++ni) {
            int col = col0 + 16 * ni + lm;
            float bias = b2[col];
            #pragma unroll
            for (int r = 0; r < 4; ++r) {
                int grow = row0 + 16 * mi + 4 * q + r;
                if (grow >= M) continue;
                float v = acc2[mi][ni][r] + bias;
                xF[(size_t)grow * HD + col] = v;
                xB[(size_t)grow * HD + col] = f2bf(v);
            }
        }
}

// ---------------- fused update+LN ----------------
// hid = relu(x@u1t + Hagg@w2u + ub1 + deg*b2u1); upd = hid@u2 + ub2; x = LN(x+upd)*g + bb.

__global__ __launch_bounds__(256) void upd_ln(
    const ushort_t* __restrict__ xb, const ushort_t* __restrict__ B1t,
    const ushort_t* __restrict__ Hb, const ushort_t* __restrict__ B2t,
    const ushort_t* __restrict__ B3t,
    const float* __restrict__ b1, const float* __restrict__ degf,
    const float* __restrict__ bias2, const float* __restrict__ b3,
    const float* __restrict__ g, const float* __restrict__ bb,
    float* __restrict__ xF, ushort_t* __restrict__ xB, int M)
{
    __shared__ char hid[32 * 512];
    __shared__ float pS[4][32], pQ[4][32], muv[32], ivv[32];
    int tid = threadIdx.x;
    int w = tid >> 6, lane = tid & 63;
    int lm = lane & 15, q = lane >> 4, lk = q * 8;
    int row0 = blockIdx.x * 32;
    int col0 = w * 64;
    int ra = min(row0 + lm, M - 1), rb = min(row0 + 16 + lm, M - 1);

    f32x4 acc[2][4] = {};
    #pragma unroll
    for (int pass = 0; pass < 2; ++pass) {
        const ushort_t* Ap = pass ? Hb : xb;
        const ushort_t* Bp = pass ? B2t : B1t;
        #pragma unroll
        for (int k0 = 0; k0 < HD; k0 += 32) {
            bf16x8 a0 = *(const bf16x8*)(Ap + (size_t)ra * HD + k0 + lk);
            bf16x8 a1 = *(const bf16x8*)(Ap + (size_t)rb * HD + k0 + lk);
            #pragma unroll
            for (int ni = 0; ni < 4; ++ni) {
                bf16x8 b = *(const bf16x8*)(Bp + (size_t)(col0 + 16 * ni + lm) * HD + k0 + lk);
                acc[0][ni] = __builtin_amdgcn_mfma_f32_16x16x32_bf16(a0, b, acc[0][ni], 0, 0, 0);
                acc[1][ni] = __builtin_amdgcn_mfma_f32_16x16x32_bf16(a1, b, acc[1][ni], 0, 0, 0);
            }
        }
    }
    // bias + relu -> LDS
    #pragma unroll
    for (int mi = 0; mi < 2; ++mi)
        #pragma unroll
        for (int r = 0; r < 4; ++r) {
            int row = 16 * mi + 4 * q + r;
            float dg = degf[min(row0 + row, M - 1)];
            #pragma unroll
            for (int ni = 0; ni < 4; ++ni) {
                int col = col0 + 16 * ni + lm;
                float v = fmaxf(acc[mi][ni][r] + b1[col] + dg * bias2[col], 0.f);
                *(ushort_t*)(hid + swz(row, col * 2)) = f2bf(v);
            }
        }
    __syncthreads();
    // upd = hid @ u2
    f32x4 acc2[2][4] = {};
    #pragma unroll
    for (int k0 = 0; k0 < HD; k0 += 32) {
        int bk = (k0 + lk) * 2;
        bf16x8 a0 = *(const bf16x8*)(hid + swz(lm, bk));
        bf16x8 a1 = *(const bf16x8*)(hid + swz(16 + lm, bk));
        #pragma unroll
        for (int ni = 0; ni < 4; ++ni) {
            bf16x8 b = *(const bf16x8*)(B3t + (size_t)(col0 + 16 * ni + lm) * HD + k0 + lk);
            acc2[0][ni] = __builtin_amdgcn_mfma_f32_16x16x32_bf16(a0, b, acc2[0][ni], 0, 0, 0);
            acc2[1][ni] = __builtin_amdgcn_mfma_f32_16x16x32_bf16(a1, b, acc2[1][ni], 0, 0, 0);
        }
    }
    // v = x + upd + b3; in-place rows owned exclusively by this block
    #pragma unroll
    for (int mi = 0; mi < 2; ++mi)
        #pragma unroll
        for (int r = 0; r < 4; ++r) {
            int grow = min(row0 + 16 * mi + 4 * q + r, M - 1);
            #pragma unroll
            for (int ni = 0; ni < 4; ++ni) {
                int col = col0 + 16 * ni + lm;
                acc2[mi][ni][r] += b3[col] + xF[(size_t)grow * HD + col];
            }
        }
    // per-row partial sums (this wave's 64 cols)
    #pragma unroll
    for (int mi = 0; mi < 2; ++mi)
        #pragma unroll
        for (int r = 0; r < 4; ++r) {
            float s = 0.f, qq = 0.f;
            #pragma unroll
            for (int ni = 0; ni < 4; ++ni) {
                float v = acc2[mi][ni][r];
                s += v; qq += v * v;
            }
            #pragma unroll
            for (int off = 1; off < 16; off <<= 1) {
                s += __shfl_xor(s, off);
                qq += __shfl_xor(qq, off);
            }
            if (lm == 0) {
                int row = 16 * mi + 4 * q + r;
                pS[w][row] = s; pQ[w][row] = qq;
            }
        }
    __syncthreads();
    if (tid < 32) {
        float s = pS[0][tid] + pS[1][tid] + pS[2][tid] + pS[3][tid];
        float qq = pQ[0][tid] + pQ[1][tid] + pQ[2][tid] + pQ[3][tid];
        float mu = s * (1.0f / HD);
        float var = qq * (1.0f / HD) - mu * mu;
        muv[tid] = mu;
        ivv[tid] = rsqrtf(var + 1e-5f);
    }
    __syncthreads();
    #pragma unroll
    for (int mi = 0; mi < 2; ++mi)
        #pragma unroll
        for (int r = 0; r < 4; ++r) {
            int row = 16 * mi + 4 * q + r;
            int grow = row0 + row;
            if (grow >= M) continue;
            float mu = muv[row], iv = ivv[row];
            #pragma unroll
            for (int ni = 0; ni < 4; ++ni) {
                int col = col0 + 16 * ni + lm;
                float o = (acc2[mi][ni][r] - mu) * iv * g[col] + bb[col];
                xF[(size_t)grow * HD + col] = o;
                xB[(size_t)grow * HD + col] = f2bf(o);
            }
        }
}

// ---------------- edge aggregation ----------------

__global__ __launch_bounds__(256) void edge_agg(
    const ushort_t* __restrict__ Pb, const float* __restrict__ Qb,
    const int* __restrict__ row_start, const int* __restrict__ srcs,
    ushort_t* __restrict__ Haggb)
{
    int node = blockIdx.x * 4 + (threadIdx.x >> 6);
    int lane = threadIdx.x & 63;
    int c4 = lane * 4;
    float4 qb = *(const float4*)(Qb + (size_t)node * HD + c4);
    float4 acc = {0.f, 0.f, 0.f, 0.f};
    int j = row_start[node], e = row_start[node + 1];
    for (; j + 4 <= e; j += 4) {
        int s0 = srcs[j], s1 = srcs[j + 1], s2 = srcs[j + 2], s3 = srcs[j + 3];
        ushort4 p0 = *(const ushort4*)(Pb + (size_t)s0 * HD + c4);
        ushort4 p1 = *(const ushort4*)(Pb + (size_t)s1 * HD + c4);
        ushort4 p2 = *(const ushort4*)(Pb + (size_t)s2 * HD + c4);
        ushort4 p3 = *(const ushort4*)(Pb + (size_t)s3 * HD + c4);
        acc.x += fmaxf(bf2f(p0.x) + qb.x, 0.f) + fmaxf(bf2f(p1.x) + qb.x, 0.f)
               + fmaxf(bf2f(p2.x) + qb.x, 0.f) + fmaxf(bf2f(p3.x) + qb.x, 0.f);
        acc.y += fmaxf(bf2f(p0.y) + qb.y, 0.f) + fmaxf(bf2f(p1.y) + qb.y, 0.f)
               + fmaxf(bf2f(p2.y) + qb.y, 0.f) + fmaxf(bf2f(p3.y) + qb.y, 0.f);
        acc.z += fmaxf(bf2f(p0.z) + qb.z, 0.f) + fmaxf(bf2f(p1.z) + qb.z, 0.f)
               + fmaxf(bf2f(p2.z) + qb.z, 0.f) + fmaxf(bf2f(p3.z) + qb.z, 0.f);
        acc.w += fmaxf(bf2f(p0.w) + qb.w, 0.f) + fmaxf(bf2f(p1.w) + qb.w, 0.f)
               + fmaxf(bf2f(p2.w) + qb.w, 0.f) + fmaxf(bf2f(p3.w) + qb.w, 0.f);
    }
    for (; j < e; ++j) {
        int s0 = srcs[j];
        ushort4 p0 = *(const ushort4*)(Pb + (size_t)s0 * HD + c4);
        acc.x += fmaxf(bf2f(p0.x) + qb.x, 0.f);
        acc.y += fmaxf(bf2f(p0.y) + qb.y, 0.f);
        acc.z += fmaxf(bf2f(p0.z) + qb.z, 0.f);
        acc.w += fmaxf(bf2f(p0.w) + qb.w, 0.f);
    }
    ushort4 o = { f2bf(acc.x), f2bf(acc.y), f2bf(acc.z), f2bf(acc.w) };
    *(ushort4*)(Haggb + (size_t)node * HD + c4) = o;
}

// ---------------- readout ----------------

__global__ __launch_bounds__(256) void colsum(const float* __restrict__ x,
                                              float* __restrict__ gsum, int n) {
    int c = threadIdx.x;
    int r0 = blockIdx.x * 64;
    int r1 = min(r0 + 64, n);
    float s = 0.f;
    for (int r = r0; r < r1; ++r) s += x[(size_t)r * HD + c];
    atomicAdd(&gsum[c], s);
}

__global__ __launch_bounds__(256) void readout_mlp(
    const float* __restrict__ gsum,
    const float* __restrict__ w1, const float* __restrict__ b1,
    const float* __restrict__ w2, const float* __restrict__ b2,
    float* __restrict__ out, float invn)
{
    __shared__ float gl[HD], h1[HD];
    int c = threadIdx.x;
    gl[c] = gsum[c] * invn;
    __syncthreads();
    float a = b1[c];
    for (int k = 0; k < HD; ++k) a += gl[k] * w1[k * HD + c];
    h1[c] = fmaxf(a, 0.f);
    __syncthreads();
    float o = b2[c];
    for (int k = 0; k < HD; ++k) o += h1[k] * w2[k * HD + c];
    out[c] = o;
}

// ---------------- orchestration ----------------

extern "C" void kernel_launch(void* const* d_in, const int* in_sizes, int n_in,
                              void* d_out, int out_size, void* d_ws, size_t ws_size,
                              hipStream_t stream) {
    const float* nf    = (const float*)d_in[0];
    const int*   ei    = (const int*)d_in[1];
    const float* ne_w1 = (const float*)d_in[2];
    const float* ne_b1 = (const float*)d_in[3];
    const float* ne_w2 = (const float*)d_in[4];
    const float* ne_b2 = (const float*)d_in[5];
    const float* mw1   = (const float*)d_in[6];
    const float* mb1   = (const float*)d_in[7];
    const float* mw2   = (const float*)d_in[8];
    const float* mb2   = (const float*)d_in[9];
    const float* uw1   = (const float*)d_in[10];
    const float* ub1   = (const float*)d_in[11];
    const float* uw2   = (const float*)d_in[12];
    const float* ub2   = (const float*)d_in[13];
    const float* lng   = (const float*)d_in[14];
    const float* lnb   = (const float*)d_in[15];
    const float* rw1   = (const float*)d_in[16];
    const float* rb1   = (const float*)d_in[17];
    const float* rw2   = (const float*)d_in[18];
    const float* rb2   = (const float*)d_in[19];

    const int* e_src = ei;
    const int* e_dst = ei + NE;

    char* w = (char*)d_ws;
    size_t off = 0;
    auto alloc = [&](size_t bytes) -> void* {
        void* p = w + off;
        off = (off + bytes + 255) & ~(size_t)255;
        return p;
    };
    const size_t NF32 = (size_t)NN * HD * sizeof(float);
    const size_t NF16 = (size_t)NN * HD * sizeof(ushort_t);
    const size_t WM16 = (size_t)HD * HD * sizeof(ushort_t);

    float* x    = (float*)alloc(NF32);
    float* Qf   = (float*)alloc(NF32);
    float* gsum = (float*)alloc(HD * sizeof(float));
    float* degf = (float*)alloc(NN * sizeof(float));
    float* b2u1 = (float*)alloc(NL * HD * sizeof(float));

    ushort_t* nfb   = (ushort_t*)alloc(NF16);
    ushort_t* xb    = (ushort_t*)alloc(NF16);
    ushort_t* Pb    = (ushort_t*)alloc(NF16);
    ushort_t* Haggb = (ushort_t*)alloc(NF16);
    ushort_t* neT1  = (ushort_t*)alloc(WM16);
    ushort_t* neT2  = (ushort_t*)alloc(WM16);
    ushort_t* w1tT  = (ushort_t*)alloc(NL * WM16);
    ushort_t* w1bT  = (ushort_t*)alloc(NL * WM16);
    ushort_t* u1tT  = (ushort_t*)alloc(NL * WM16);
    ushort_t* u1bT  = (ushort_t*)alloc(NL * WM16);
    ushort_t* u2T   = (ushort_t*)alloc(NL * WM16);
    ushort_t* w2uT  = (ushort_t*)alloc(NL * WM16);
    ushort_t* w2rmb = (ushort_t*)alloc(NL * WM16);

    int* deg       = (int*)alloc(NN * sizeof(int));
    int* row_start = (int*)alloc((NN + 1) * sizeof(int));
    int* cursor    = (int*)alloc(NN * sizeof(int));
    int* srcs      = (int*)alloc(NE * sizeof(int));

    hipMemsetAsync(deg, 0, NN * sizeof(int), stream);
    hipMemsetAsync(gsum, 0, HD * sizeof(float), stream);

    // CSR build
    hist_deg<<<(NE + 255) / 256, 256, 0, stream>>>(e_dst, deg, NE);
    scan_csr<<<1, 1024, 0, stream>>>(deg, row_start, cursor, degf, NN);
    scatter_src<<<(NE + 255) / 256, 256, 0, stream>>>(e_src, e_dst, cursor, srcs, NE);

    // conversions
    cast_bf16<<<(NN * HD / 4 + 255) / 256, 256, 0, stream>>>(nf, nfb, NN * HD / 4);
    cast_bf16<<<(NL * HD * HD / 4 + 255) / 256, 256, 0, stream>>>(mw2, w2rmb, NL * HD * HD / 4);

    TArgs ta;
    ta.d[0] = { ne_w1, neT1 };
    ta.d[1] = { ne_w2, neT2 };
    for (int l = 0; l < NL; ++l) {
        const float* w1l = mw1 + (size_t)l * 2 * HD * HD;
        const float* u1l = uw1 + (size_t)l * 2 * HD * HD;
        ta.d[2 + l]  = { w1l,                       w1tT + (size_t)l * HD * HD };
        ta.d[5 + l]  = { w1l + (size_t)HD * HD,     w1bT + (size_t)l * HD * HD };
        ta.d[8 + l]  = { u1l,                       u1tT + (size_t)l * HD * HD };
        ta.d[11 + l] = { u1l + (size_t)HD * HD,     u1bT + (size_t)l * HD * HD };
        ta.d[14 + l] = { uw2 + (size_t)l * HD * HD, u2T + (size_t)l * HD * HD };
    }
    conv_t<<<dim3(16, 17), 256, 0, stream>>>(ta);
    bias_compose<<<NL, 256, 0, stream>>>(mb2, uw1, b2u1);
    gemm_w2u<<<dim3(4, 4, NL), 256, 0, stream>>>(u1bT, w2rmb, w2uT);

    // encoder (fused 2-layer MLP)
    enc_fused<<<(NN + 31) / 32, 256, 0, stream>>>(nfb, neT1, neT2, ne_b1, ne_b2, x, xb, NN);

    dim3 pqgrid((NN + 63) / 64, HD / 64);
    for (int l = 0; l < NL; ++l) {
        gemm_pq<<<pqgrid, 256, 0, stream>>>(xb, w1tT + (size_t)l * HD * HD,
                                            w1bT + (size_t)l * HD * HD, mb1 + (size_t)l * HD,
                                            Pb, Qf, NN);
        edge_agg<<<NN / 4, 256, 0, stream>>>(Pb, Qf, row_start, srcs, Haggb);
        upd_ln<<<(NN + 31) / 32, 256, 0, stream>>>(
            xb, u1tT + (size_t)l * HD * HD, Haggb, w2uT + (size_t)l * HD * HD,
            u2T + (size_t)l * HD * HD, ub1 + (size_t)l * HD, degf,
            b2u1 + (size_t)l * HD, ub2 + (size_t)l * HD,
            lng + (size_t)l * HD, lnb + (size_t)l * HD, x, xb, NN);
    }

    // readout
    colsum<<<(NN + 63) / 64, 256, 0, stream>>>(x, gsum, NN);
    readout_mlp<<<1, 256, 0, stream>>>(gsum, rw1, rb1, rw2, rb2, (float*)d_out, 1.0f / NN);
}